// Round 9
// baseline (190.179 us; speedup 1.0000x reference)
//
#include <hip/hip_runtime.h>

#define HW    4096
#define CDIM  64
#define KCB   1024
#define NELM  8388608
#define NPTS  131072
#define NQ    4
#define NBLKA 2048         // (NPTS/256 pt-groups) * NQ quarters
#define NBLKB 1024         // NPTS/128

typedef __attribute__((ext_vector_type(8))) short  short8;
typedef __attribute__((ext_vector_type(4))) float  float4v;

__device__ inline unsigned short f2bf(float v) {
    unsigned u = __builtin_bit_cast(unsigned, v);
    unsigned r = u + 0x7FFF + ((u >> 16) & 1);   // RNE
    return (unsigned short)(r >> 16);
}
__device__ inline unsigned umin32(unsigned a, unsigned b) { return a < b ? a : b; }

// ws: [0..1023] e_sq+1.0 | [1024] accum | [1025] ticket | [2048..] cbB (128 KB, frag order)
//     [34816..] pmin4: NQ x NPTS packed u32
__global__ void vq_prep(const float* __restrict__ cb, float* __restrict__ esqb,
                        float* __restrict__ accum, int* __restrict__ cnt,
                        unsigned short* __restrict__ cbB) {
    int u = blockIdx.x * 256 + threadIdx.x;      // 0..8191
    if (u == 0) { *accum = 0.0f; *cnt = 0; }
    if (u < KCB) {
        const float* row = cb + u * CDIM;
        float s = 0.0f;
        #pragma unroll
        for (int c = 0; c < CDIM; ++c) s = fmaf(row[c], row[c], s);
        esqb[u] = s + 1.0f;                      // +1 bias => packed distances strictly positive
    }
    // B-frag order (verified R2-R8); B carries -2*e, A carries raw x.
    int k = u >> 3, s7 = u & 7;
    const float* src = cb + k * CDIM + s7 * 8;
    unsigned short tmp[8];
    #pragma unroll
    for (int j = 0; j < 8; ++j) tmp[j] = f2bf(-2.0f * src[j]);
    int kt = k >> 4, n = k & 15, f = s7 >> 2, q = s7 & 3;
    int dst = (((kt * 2 + f) * 64) + q * 16 + n) * 8;
    *(short8*)(cbB + dst) = *(short8*)tmp;
}

// Argmin: 256 points x 256 codes per block; 4 blocks resident + 4 queued per CU.
__global__ __launch_bounds__(256, 4)   // 16 waves/CU, VGPR cap 128
void vq_argmin(const float* __restrict__ x,
               const float* __restrict__ esqb,
               const unsigned short* __restrict__ cbB,
               unsigned* __restrict__ pmin4,
               float* __restrict__ accum) {
    __shared__ unsigned short bbuf[256 * 64];    // 32 KB quarter codebook
    __shared__ float lesq[256];                  // 1 KB
    __shared__ float wred[4];

    const int t       = threadIdx.x;             // 0..255, 4 waves
    const int quarter = blockIdx.x & 3;          // low bits: group's quarters land near-in-time
    const int n0      = (blockIdx.x >> 2) * 256;
    const int b       = n0 >> 12;
    const int hw0     = n0 & (HW - 1);
    const int l       = t & 63, w = t >> 6;
    const int col     = l & 15, q = l >> 4;
    const int p0      = w * 64;                  // wave owns 64 points

    // ---- stage quarter codebook (32 KB): 8 rounds x 256 thr x 16 B ----
    const unsigned short* gsrc = cbB + quarter * 16384;
    #pragma unroll
    for (int i = 0; i < 8; ++i) {
        int off = (i * 256 + t) * 8;
        __builtin_amdgcn_global_load_lds(
            (const __attribute__((address_space(1))) unsigned int*)(gsrc + off),
            (__attribute__((address_space(3))) unsigned int*)(&bbuf[off]),
            16, 0, 0);
    }
    lesq[t] = esqb[quarter * 256 + t];

    // ---- A fragments direct from global (overlaps staging): 64 pts/wave ----
    short8 a[4][2];
    float  xs = 0.0f;
    const float* xbase = x + (size_t)b * CDIM * HW + hw0;
    #pragma unroll
    for (int mt = 0; mt < 4; ++mt) {
        const int p = p0 + mt * 16 + col;
        #pragma unroll
        for (int f = 0; f < 2; ++f) {
            unsigned short tmp[8];
            #pragma unroll
            for (int j = 0; j < 8; ++j) {
                float v = xbase[(size_t)(f * 32 + q * 8 + j) * HW + p];
                xs = fmaf(v, v, xs);
                tmp[j] = f2bf(v);
            }
            a[mt][f] = *(short8*)tmp;
        }
    }
    __syncthreads();   // bbuf + lesq resident

    // ---- k-loop: 16 kts; named-register prefetch; packed argmin ----
    unsigned bm[16];
    #pragma unroll
    for (int i = 0; i < 16; ++i) bm[i] = 0xFFFFFFFFu;
    unsigned cand = (unsigned)(quarter * 256 + col);
    const short8* bl = ((const short8*)bbuf) + l;

    auto kt_body = [&](short8 b0, short8 b1, float ev) {
        float4v c0 = {ev, ev, ev, ev};
        #pragma unroll
        for (int mt = 0; mt < 4; ++mt) {
            float4v acc = __builtin_amdgcn_mfma_f32_16x16x32_bf16(a[mt][0], b0, c0, 0, 0, 0);
            acc = __builtin_amdgcn_mfma_f32_16x16x32_bf16(a[mt][1], b1, acc, 0, 0, 0);
            #pragma unroll
            for (int r = 0; r < 4; ++r) {
                unsigned pk = (__builtin_bit_cast(unsigned, acc[r]) & 0xFFFFFC00u) | cand;
                bm[mt * 4 + r] = umin32(bm[mt * 4 + r], pk);
            }
        }
        cand += 16;
    };

    float  E0 = lesq[col],            E1 = lesq[16 + col];
    short8 A0 = bl[0],   A1 = bl[64];
    short8 A2 = bl[128], A3 = bl[192];
    #pragma unroll
    for (int kt = 0; kt < 16; kt += 2) {
        short8 t0 = A0, t1 = A1, t2 = A2, t3 = A3;
        float  e0 = E0, e1 = E1;
        if (kt + 2 < 16) {
            E0 = lesq[(kt + 2) * 16 + col];
            E1 = lesq[(kt + 3) * 16 + col];
            A0 = bl[(kt + 2) * 128];  A1 = bl[(kt + 2) * 128 + 64];
            A2 = bl[(kt + 3) * 128];  A3 = bl[(kt + 3) * 128 + 64];
        }
        kt_body(t0, t1, e0);
        kt_body(t2, t3, e1);
    }

    // ---- argmin across the 16 code-columns (packed butterfly) ----
    #pragma unroll
    for (int s = 1; s < 16; s <<= 1)
        #pragma unroll
        for (int i = 0; i < 16; ++i) {
            unsigned o = (unsigned)__shfl_xor((int)bm[i], s, 64);
            bm[i] = umin32(bm[i], o);
        }

    // per-quarter result, contention-free stores (no atomics)
    if (col == 0) {
        unsigned* pq = pmin4 + (size_t)quarter * NPTS + n0 + p0;
        #pragma unroll
        for (int mt = 0; mt < 4; ++mt)
            #pragma unroll
            for (int r = 0; r < 4; ++r)
                pq[mt * 16 + q * 4 + r] = bm[mt * 4 + r];
    }

    // ---- x_sq contribution (exact, once per point: quarter 0 only) ----
    if (quarter == 0) {
        float lp = xs;
        #pragma unroll
        for (int off = 32; off > 0; off >>= 1) lp += __shfl_down(lp, off, 64);
        if (l == 0) wred[w] = lp;
        __syncthreads();
        if (t == 0) atomicAdd(accum, wred[0] + wred[1] + wred[2] + wred[3]);
    }
}

// Scatter: combine quarters, z_q write, loss finalize. 128 points per block.
__global__ __launch_bounds__(256)
void vq_scatter(const float* __restrict__ cb,
                const unsigned* __restrict__ pmin4,
                float* __restrict__ zq,
                float* __restrict__ accum,
                int* __restrict__ cnt,
                float* __restrict__ loss_out) {
    __shared__ int   idxl[128];
    __shared__ float wredb[2];

    const int t   = threadIdx.x;                 // 0..255
    const int n0  = blockIdx.x * 128;
    const int b   = n0 >> 12;
    const int hw0 = n0 & (HW - 1);

    if (t < 128) {
        unsigned u = pmin4[n0 + t];
        u = umin32(u, pmin4[1 * NPTS + n0 + t]);
        u = umin32(u, pmin4[2 * NPTS + n0 + t]);
        u = umin32(u, pmin4[3 * NPTS + n0 + t]);
        idxl[t] = (int)(u & 1023u);
        float dm1 = __builtin_bit_cast(float, u & 0xFFFFFC00u) - 1.0f;  // e_sq - 2dot
        #pragma unroll
        for (int off = 32; off > 0; off >>= 1) dm1 += __shfl_down(dm1, off, 64);
        if ((t & 63) == 0) wredb[t >> 6] = dm1;
    }
    __syncthreads();
    if (t == 0) atomicAdd(accum, wredb[0] + wredb[1]);

    // thread (pt, h): gather 32 exact fp32 channels of winning row, store strided-coalesced
    const int pt = t & 127, h = t >> 7;
    const float4v* crow = (const float4v*)(cb + (size_t)idxl[pt] * CDIM + h * 32);
    float* zp = zq + ((size_t)b * CDIM + h * 32) * HW + hw0 + pt;
    #pragma unroll
    for (int i = 0; i < 8; ++i) {
        float4v vv = crow[i];
        zp[(size_t)(i * 4 + 0) * HW] = vv[0];
        zp[(size_t)(i * 4 + 1) * HW] = vv[1];
        zp[(size_t)(i * 4 + 2) * HW] = vv[2];
        zp[(size_t)(i * 4 + 3) * HW] = vv[3];
    }

    // ticket: last block writes the loss
    if (t == 0) {
        __threadfence();
        int tk = atomicAdd(cnt, 1);
        if (tk == NBLKB - 1) {
            float tot = atomicAdd(accum, 0.0f);
            loss_out[0] = 1.25f * tot * (1.0f / (float)NELM);
        }
    }
}

extern "C" void kernel_launch(void* const* d_in, const int* in_sizes, int n_in,
                              void* d_out, int out_size, void* d_ws, size_t ws_size,
                              hipStream_t stream) {
    const float* x  = (const float*)d_in[0];
    const float* cb = (const float*)d_in[1];
    float* esqb  = (float*)d_ws;
    float* accum = esqb + KCB;
    int*   cnt   = (int*)(esqb + KCB + 1);
    unsigned short* cbB = (unsigned short*)(esqb + 2048);   // 128 KB
    unsigned* pmin4 = (unsigned*)(esqb + 2048 + 32768);     // NQ x NPTS u32 (2 MB)
    float* zq   = (float*)d_out;
    float* loss = zq + NELM;

    vq_prep   <<<32,    256, 0, stream>>>(cb, esqb, accum, cnt, cbB);
    vq_argmin <<<NBLKA, 256, 0, stream>>>(x, esqb, cbB, pmin4, accum);
    vq_scatter<<<NBLKB, 256, 0, stream>>>(cb, pmin4, zq, accum, cnt, loss);
}